// Round 10
// baseline (252.835 us; speedup 1.0000x reference)
//
#include <hip/hip_runtime.h>
#include <math.h>

#define BROWS 65536
#define DIMS 512
#define NCLS 256
#define MARGIN 0.3f
#define EPSN 1e-12f
#define NSTRIP 64      // 64 strips x 1024 rows
#define SROWS 1024
#define LSPL 3         // 8 splits/class in ksumn
#define TSPL 8         // 8 splits/class in kterm2

// K1: per-strip label histogram (LDS atomics only).
__global__ void __launch_bounds__(256) khist2(const int* __restrict__ labels,
                                              int* __restrict__ hist) {
  __shared__ int h[NCLS];
  int t = threadIdx.x, s = blockIdx.x;
  h[t] = 0;
  __syncthreads();
  int base = s * SROWS + t;
#pragma unroll
  for (int k = 0; k < SROWS / 256; ++k) atomicAdd(&h[labels[base + k * 256]], 1);
  __syncthreads();
  hist[s * NCLS + t] = h[t];
}

// K2: per-strip deterministic scatter (bases + counts published by block 0).
__global__ void __launch_bounds__(256) kscatter2(const int* __restrict__ labels,
                                                 const int* __restrict__ hist,
                                                 int* __restrict__ bases,
                                                 float* __restrict__ counts,
                                                 int* __restrict__ rowidx) {
  int t = threadIdx.x, s = blockIdx.x;  // t = class
  int run = 0, myoff = 0;
  for (int s2 = 0; s2 < NSTRIP; ++s2) {
    int h = hist[s2 * NCLS + t];        // coalesced across t
    if (s2 < s) myoff += h;
    run += h;
  }
  __shared__ int sc[NCLS];
  sc[t] = run;
  __syncthreads();
  int v = sc[t];
  for (int off = 1; off < NCLS; off <<= 1) {
    int add = (t >= off) ? sc[t - off] : 0;
    __syncthreads();
    sc[t] = v = v + add;
    __syncthreads();
  }
  int excl = (t == 0) ? 0 : sc[t - 1];
  if (s == 0) {
    bases[t] = excl;
    counts[t] = (float)run;
  }
  __shared__ int loff[NCLS];
  __shared__ int cur[NCLS];
  loff[t] = excl + myoff;
  cur[t] = 0;
  __syncthreads();
  int rbase = s * SROWS + t;
#pragma unroll
  for (int k = 0; k < SROWS / 256; ++k) {
    int r = rbase + k * 256;
    int lab = labels[r];
    int lpos = atomicAdd(&cur[lab], 1);
    rowidx[loff[lab] + lpos] = r;
  }
}

// K3: fused row-norm + per-class segment sum. 8-row predicated unroll keeps
// 16 independent dwordx4 loads in flight per wave (tails masked, not scalar).
__global__ void __launch_bounds__(256) ksumn(const float* __restrict__ emb,
                                             const int* __restrict__ rowidx,
                                             const int* __restrict__ bases,
                                             const float* __restrict__ counts,
                                             float* __restrict__ invnorm,
                                             float* __restrict__ partials) {
  int cls = blockIdx.x >> LSPL;
  int sp = blockIdx.x & ((1 << LSPL) - 1);
  int t = threadIdx.x, w = t >> 6, lane = t & 63;
  int base = bases[cls];
  int cnt = (int)counts[cls];
  int i0 = (cnt * sp) >> LSPL;
  int i1 = (cnt * (sp + 1)) >> LSPL;
  int n = i1 - i0;
  int j0 = i0 + ((n * w) >> 2);
  int j1 = i0 + ((n * (w + 1)) >> 2);
  const float4* ebase = reinterpret_cast<const float4*>(emb);
  int cq = lane * 2;  // float4 index: cols [lane*8, lane*8+8)
  float4 acc0 = make_float4(0.f, 0.f, 0.f, 0.f);
  float4 acc1 = make_float4(0.f, 0.f, 0.f, 0.f);
  for (int j = j0; j < j1; j += 8) {
    int r[8];
    float msk[8];
#pragma unroll
    for (int k = 0; k < 8; ++k) {
      int jj = (j + k < j1) ? (j + k) : (j1 - 1);
      r[k] = rowidx[base + jj];
      msk[k] = (j + k < j1) ? 1.0f : 0.0f;
    }
    float4 a[8], b[8];
#pragma unroll
    for (int k = 0; k < 8; ++k) {
      const float4* p = ebase + (size_t)r[k] * (DIMS / 4) + cq;
      a[k] = p[0];
      b[k] = p[1];
    }
    float s[8];
#pragma unroll
    for (int k = 0; k < 8; ++k)
      s[k] = a[k].x*a[k].x + a[k].y*a[k].y + a[k].z*a[k].z + a[k].w*a[k].w
           + b[k].x*b[k].x + b[k].y*b[k].y + b[k].z*b[k].z + b[k].w*b[k].w;
#pragma unroll
    for (int off = 1; off < 64; off <<= 1) {
#pragma unroll
      for (int k = 0; k < 8; ++k) s[k] += __shfl_xor(s[k], off, 64);
    }
    float qv[8], q[8];
#pragma unroll
    for (int k = 0; k < 8; ++k) {
      qv[k] = 1.0f / fmaxf(sqrtf(s[k]), EPSN);
      q[k] = qv[k] * msk[k];
    }
    if (lane == 0) {
#pragma unroll
      for (int k = 0; k < 8; ++k)
        if (j + k < j1) invnorm[r[k]] = qv[k];
    }
#pragma unroll
    for (int k = 0; k < 8; ++k) {
      acc0.x += a[k].x * q[k]; acc0.y += a[k].y * q[k];
      acc0.z += a[k].z * q[k]; acc0.w += a[k].w * q[k];
      acc1.x += b[k].x * q[k]; acc1.y += b[k].y * q[k];
      acc1.z += b[k].z * q[k]; acc1.w += b[k].w * q[k];
    }
  }
  __shared__ float lds[4][DIMS];
  *reinterpret_cast<float4*>(&lds[w][lane * 8]) = acc0;
  *reinterpret_cast<float4*>(&lds[w][lane * 8 + 4]) = acc1;
  __syncthreads();
  float o0 = lds[0][t] + lds[1][t] + lds[2][t] + lds[3][t];
  float o1 = lds[0][t + 256] + lds[1][t + 256] + lds[2][t + 256] + lds[3][t + 256];
  float* outp = partials + ((size_t)sp * NCLS + cls) * DIMS;
  outp[t] = o0;
  outp[t + 256] = o1;
}

// K4: reduce split partials -> mean -> L2-normalized centroid.
__global__ void __launch_bounds__(256) kcent(const float* __restrict__ partials,
                                             const float* __restrict__ counts,
                                             float* __restrict__ cent) {
  int cls = blockIdx.x, t = threadIdx.x;
  float s0 = 0.0f, s1 = 0.0f;
#pragma unroll
  for (int sp = 0; sp < (1 << LSPL); ++sp) {
    const float* p = partials + ((size_t)sp * NCLS + cls) * DIMS;
    s0 += p[t];
    s1 += p[t + 256];
  }
  float cm = fmaxf(counts[cls], 1.0f);
  float m0 = s0 / cm, m1 = s1 / cm;
  __shared__ float red[256];
  red[t] = m0 * m0 + m1 * m1;
  __syncthreads();
  for (int off = 128; off > 0; off >>= 1) {
    if (t < off) red[t] += red[t + off];
    __syncthreads();
  }
  float inv = 1.0f / fmaxf(sqrtf(red[0]), EPSN);
  cent[(size_t)cls * DIMS + t] = m0 * inv;
  cent[(size_t)cls * DIMS + t + 256] = m1 * inv;
}

// K5: nearest-centroid argmin (lexicographic ties = jnp.argmin).
__global__ void __launch_bounds__(256) knearest(const float* __restrict__ cent,
                                                const float* __restrict__ counts,
                                                int* __restrict__ nearest) {
  int i = blockIdx.x, j = threadIdx.x;
  __shared__ float ci[DIMS];
  ci[j] = cent[(size_t)i * DIMS + j];
  ci[j + 256] = cent[(size_t)i * DIMS + j + 256];
  __syncthreads();
  const float4* cj = reinterpret_cast<const float4*>(cent + (size_t)j * DIMS);
  float dot = 0.0f;
#pragma unroll 8
  for (int k = 0; k < DIMS / 4; ++k) {
    float4 v = cj[k];
    dot += v.x * ci[4*k] + v.y * ci[4*k+1] + v.z * ci[4*k+2] + v.w * ci[4*k+3];
  }
  float dist = sqrtf(fmaxf(2.0f - 2.0f * dot, 0.0f));
  bool valid = (j != i) && (counts[j] > 0.0f);
  float dv = valid ? dist : INFINITY;
  __shared__ float sd[256];
  __shared__ int si[256];
  sd[j] = dv; si[j] = j;
  __syncthreads();
  for (int off = 128; off > 0; off >>= 1) {
    if (j < off) {
      float o = sd[j + off]; int oi = si[j + off];
      if (o < sd[j] || (o == sd[j] && oi < si[j])) { sd[j] = o; si[j] = oi; }
    }
    __syncthreads();
  }
  if (j == 0) nearest[i] = si[0];
}

// K6: triplet terms from f32 emb (L3-hot). 8-row predicated unroll.
__global__ void __launch_bounds__(256) kterm2(const float* __restrict__ emb,
                                              const float* __restrict__ invnorm,
                                              const int* __restrict__ rowidx,
                                              const int* __restrict__ bases,
                                              const float* __restrict__ counts,
                                              const float* __restrict__ cent,
                                              const int* __restrict__ nearest,
                                              float* __restrict__ tsums) {
  int cls = blockIdx.x >> 3;  // TSPL == 8
  int sp = blockIdx.x & (TSPL - 1);
  int t = threadIdx.x, w = t >> 6, lane = t & 63;
  int base = bases[cls];
  int cnt = (int)counts[cls];
  int ng = nearest[cls];
  int cq = lane * 2;
  const float4* pp = reinterpret_cast<const float4*>(cent + (size_t)cls * DIMS) + cq;
  const float4* pn = reinterpret_cast<const float4*>(cent + (size_t)ng * DIMS) + cq;
  float4 P0 = pp[0], P1 = pp[1], N0 = pn[0], N1 = pn[1];
  float4 d0 = make_float4(N0.x - P0.x, N0.y - P0.y, N0.z - P0.z, N0.w - P0.w);
  float4 d1 = make_float4(N1.x - P1.x, N1.y - P1.y, N1.z - P1.z, N1.w - P1.w);
  int i0 = (cnt * sp) / TSPL;
  int i1 = (cnt * (sp + 1)) / TSPL;
  int n = i1 - i0;
  int j0 = i0 + ((n * w) >> 2);
  int j1 = i0 + ((n * (w + 1)) >> 2);
  const float4* ebase = reinterpret_cast<const float4*>(emb);
  float tsum = 0.0f;
  for (int j = j0; j < j1; j += 8) {
    int r[8];
    float msk[8];
#pragma unroll
    for (int k = 0; k < 8; ++k) {
      int jj = (j + k < j1) ? (j + k) : (j1 - 1);
      r[k] = rowidx[base + jj];
      msk[k] = (j + k < j1) ? 1.0f : 0.0f;
    }
    float inv[8];
#pragma unroll
    for (int k = 0; k < 8; ++k) inv[k] = invnorm[r[k]];
    float4 a[8], b[8];
#pragma unroll
    for (int k = 0; k < 8; ++k) {
      const float4* p = ebase + (size_t)r[k] * (DIMS / 4) + cq;
      a[k] = p[0];
      b[k] = p[1];
    }
    float s[8];
#pragma unroll
    for (int k = 0; k < 8; ++k)
      s[k] = a[k].x*d0.x + a[k].y*d0.y + a[k].z*d0.z + a[k].w*d0.w
           + b[k].x*d1.x + b[k].y*d1.y + b[k].z*d1.z + b[k].w*d1.w;
#pragma unroll
    for (int off = 1; off < 64; off <<= 1) {
#pragma unroll
      for (int k = 0; k < 8; ++k) s[k] += __shfl_xor(s[k], off, 64);
    }
#pragma unroll
    for (int k = 0; k < 8; ++k)
      tsum += fmaxf(s[k] * inv[k] + MARGIN, 0.0f) * msk[k];
  }
  __shared__ float sred[4];
  if (lane == 0) sred[w] = tsum;
  __syncthreads();
  if (t == 0) tsums[blockIdx.x] = sred[0] + sred[1] + sred[2] + sred[3];
}

// K7: final present-masked mean of per-class means.
__global__ void __launch_bounds__(256) kfinal(const float* __restrict__ counts,
                                              const float* __restrict__ tsums,
                                              float* __restrict__ out) {
  int t = threadIdx.x;
  float cnt = counts[t];
  bool present = cnt > 0.0f;
  float ls = 0.0f;
#pragma unroll
  for (int k = 0; k < TSPL; ++k) ls += tsums[t * TSPL + k];
  float v = present ? ls / fmaxf(cnt, 1.0f) : 0.0f;
  float np = present ? 1.0f : 0.0f;
  __shared__ float sv[256], sp[256];
  sv[t] = v; sp[t] = np;
  __syncthreads();
  for (int off = 128; off > 0; off >>= 1) {
    if (t < off) { sv[t] += sv[t + off]; sp[t] += sp[t + off]; }
    __syncthreads();
  }
  if (t == 0) out[0] = sv[0] / fmaxf(sp[0], 1.0f);
}

extern "C" void kernel_launch(void* const* d_in, const int* in_sizes, int n_in,
                              void* d_out, int out_size, void* d_ws, size_t ws_size,
                              hipStream_t stream) {
  const float* emb = (const float*)d_in[0];
  const int* labels = (const int*)d_in[1];
  float* out = (float*)d_out;

  char* ws = (char*)d_ws;
  size_t off = 0;
  auto alloc = [&](size_t bytes) {
    char* p = ws + off;
    off += (bytes + 255) & ~(size_t)255;
    return p;
  };
  int*   hist    = (int*)alloc((size_t)NSTRIP * NCLS * 4);            // 64 KB
  int*   bases   = (int*)alloc((size_t)NCLS * 4);                     // 1 KB
  float* counts  = (float*)alloc((size_t)NCLS * 4);                   // 1 KB
  float* cent    = (float*)alloc((size_t)NCLS * DIMS * 4);            // 512 KB
  int*   nearest = (int*)alloc((size_t)NCLS * 4);                     // 1 KB
  int*   rowidx  = (int*)alloc((size_t)BROWS * 4);                    // 256 KB
  float* invnorm = (float*)alloc((size_t)BROWS * 4);                  // 256 KB
  float* tsums   = (float*)alloc((size_t)NCLS * TSPL * 4);            // 8 KB
  float* partials= (float*)alloc(((size_t)NCLS * DIMS * 4) << LSPL);  // 4 MB

  khist2<<<NSTRIP, 256, 0, stream>>>(labels, hist);
  kscatter2<<<NSTRIP, 256, 0, stream>>>(labels, hist, bases, counts, rowidx);
  ksumn<<<NCLS << LSPL, 256, 0, stream>>>(emb, rowidx, bases, counts, invnorm, partials);
  kcent<<<NCLS, 256, 0, stream>>>(partials, counts, cent);
  knearest<<<NCLS, 256, 0, stream>>>(cent, counts, nearest);
  kterm2<<<NCLS * TSPL, 256, 0, stream>>>(emb, invnorm, rowidx, bases, counts,
                                          cent, nearest, tsums);
  kfinal<<<1, 256, 0, stream>>>(counts, tsums, out);
}